// Round 7
// baseline (338.524 us; speedup 1.0000x reference)
//
#include <hip/hip_runtime.h>
#include <stdint.h>

#define M_TOT 2048   // B*C
#define N_TOT 16384  // B*F
#define K_TOT 512    // D

typedef _Float16 f16x8 __attribute__((ext_vector_type(8)));
typedef float f32x16 __attribute__((ext_vector_type(16)));

#define AS1 __attribute__((address_space(1)))
#define AS3 __attribute__((address_space(3)))

__device__ __forceinline__ void ld_lds16(const void* g, void* l) {
    __builtin_amdgcn_global_load_lds((const AS1 void*)g, (AS3 void*)l, 16, 0, 0);
}

#define BAR() do { asm volatile("" ::: "memory"); __builtin_amdgcn_s_barrier(); asm volatile("" ::: "memory"); } while (0)
#define VMC(N) asm volatile("s_waitcnt vmcnt(" #N ")" ::: "memory")

// ---------------- Kernel 1: norms + f16 hi/lo split planes ----------------
__device__ __forceinline__ void split4(float x0, float x1, float x2, float x3,
                                       uint2* hs, uint2* ls) {
    union U { _Float16 h[4]; uint2 u; } H, L;
    _Float16 h0 = (_Float16)x0; H.h[0] = h0; L.h[0] = (_Float16)(x0 - (float)h0);
    _Float16 h1 = (_Float16)x1; H.h[1] = h1; L.h[1] = (_Float16)(x1 - (float)h1);
    _Float16 h2 = (_Float16)x2; H.h[2] = h2; L.h[2] = (_Float16)(x2 - (float)h2);
    _Float16 h3 = (_Float16)x3; H.h[3] = h3; L.h[3] = (_Float16)(x3 - (float)h3);
    *hs = H.u; *ls = L.u;
}

__global__ __launch_bounds__(256) void norm_split_kernel(
    const float* __restrict__ c_feats, const float* __restrict__ f_feats,
    _Float16* __restrict__ Ah, _Float16* __restrict__ Al,
    _Float16* __restrict__ Bh, _Float16* __restrict__ Bl,
    float* __restrict__ normf)
{
    int wave = blockIdx.x * 4 + (threadIdx.x >> 6);
    int lane = threadIdx.x & 63;
    if (wave < 2048) {
        const float* row = c_feats + (size_t)wave * K_TOT;
        float4 v0 = ((const float4*)row)[lane];
        float4 v1 = ((const float4*)row)[lane + 64];
        double ss = (double)v0.x * v0.x + (double)v0.y * v0.y +
                    (double)v0.z * v0.z + (double)v0.w * v0.w +
                    (double)v1.x * v1.x + (double)v1.y * v1.y +
                    (double)v1.z * v1.z + (double)v1.w * v1.w;
        #pragma unroll
        for (int off = 32; off; off >>= 1) ss += __shfl_down(ss, off);
        double tot = __shfl(ss, 0);
        float nrm = sqrtf((float)tot);
        float a0 = v0.x / nrm, a1 = v0.y / nrm, a2 = v0.z / nrm, a3 = v0.w / nrm;
        float b0 = v1.x / nrm, b1 = v1.y / nrm, b2 = v1.z / nrm, b3 = v1.w / nrm;
        uint2 h, l;
        split4(a0, a1, a2, a3, &h, &l);
        ((uint2*)(Ah + (size_t)wave * K_TOT))[lane] = h;
        ((uint2*)(Al + (size_t)wave * K_TOT))[lane] = l;
        split4(b0, b1, b2, b3, &h, &l);
        ((uint2*)(Ah + (size_t)wave * K_TOT))[lane + 64] = h;
        ((uint2*)(Al + (size_t)wave * K_TOT))[lane + 64] = l;
    } else if (wave < 18432) {
        int fr = wave - 2048;
        const float* row = f_feats + (size_t)fr * K_TOT;
        float4 v0 = ((const float4*)row)[lane];
        float4 v1 = ((const float4*)row)[lane + 64];
        double ss = (double)v0.x * v0.x + (double)v0.y * v0.y +
                    (double)v0.z * v0.z + (double)v0.w * v0.w +
                    (double)v1.x * v1.x + (double)v1.y * v1.y +
                    (double)v1.z * v1.z + (double)v1.w * v1.w;
        #pragma unroll
        for (int off = 32; off; off >>= 1) ss += __shfl_down(ss, off);
        if (lane == 0) normf[fr] = sqrtf((float)ss);
        uint2 h, l;
        split4(v0.x, v0.y, v0.z, v0.w, &h, &l);
        ((uint2*)(Bh + (size_t)fr * K_TOT))[lane] = h;
        ((uint2*)(Bl + (size_t)fr * K_TOT))[lane] = l;
        split4(v1.x, v1.y, v1.z, v1.w, &h, &l);
        ((uint2*)(Bh + (size_t)fr * K_TOT))[lane + 64] = h;
        ((uint2*)(Bl + (size_t)fr * K_TOT))[lane + 64] = l;
    }
}

// ---------------- Kernel 2: split-f16 MFMA GEMM, 256x256, deep-vmcnt 3-phase ----------------
// R7: same geometry as R6 (256^2, BK=32, 8 waves 2Mx4N, dbuf 128 KiB LDS) but
// the vmcnt ladder now waits on loads issued 2-3 phases (>=1300 cyc) earlier,
// never inside L2 latency. Plane ladder per tile t (issue order = FIFO):
//   PH1{rd Ah,Bl | issue Ah(t+1) | 8 MFMA hl-Q0  | vmcnt(4): Bh(t) landed}
//   PH2{rd Bh    | issue Bl(t+1) | 16 MFMA hlQ1+hhQ0 | vmcnt(4): Al(t) landed}
//   PH3{rd Al    | issue Bh,Al(t+1) | 24 MFMA hhQ1+lh | vmcnt(4): Ah,Bl(t+1) landed}
// Per-acc pass order is hl,hh,lh (R6 was hl,lh,hh): S perturbation ~1e-7,
// tolerated per R6's absmax=0 evidence.
__global__ __launch_bounds__(512, 2) void mfma_gemm_kernel(
    const _Float16* __restrict__ Ah, const _Float16* __restrict__ Al,
    const _Float16* __restrict__ Bh, const _Float16* __restrict__ Bl,
    const float* __restrict__ normf,
    float* __restrict__ out)
{
    __shared__ _Float16 lds[2 * 4 * 8192];   // [buf][plane: Ah,Al,Bh,Bl][256*32]

    const int t = threadIdx.x;
    const int w = t >> 6, lane = t & 63;
    const int m32 = lane & 31, kql0 = lane >> 5;
    const int wr = w >> 2, wc = w & 3;
    const int wm = wr * 128, wn = wc * 64;

    const int bx = (int)blockIdx.x;
    const int ntile = ((bx & 7) << 3) | (bx >> 3);
    const int gm0 = (int)blockIdx.y * 256, gn0 = ntile * 256;

    // staging: thread covers chunks t and t+512 of each 256x32 plane, k-quad
    // XOR pre-swizzled on the global side (LDS dest linear).
    const int rowA = t >> 2;
    const int kq8 = ((t & 3) ^ ((rowA >> 1) & 3)) * 8;
    const _Float16* const gA   = Ah + (size_t)(gm0 + rowA) * K_TOT + kq8;
    const _Float16* const gB   = Bh + (size_t)(gn0 + rowA) * K_TOT + kq8;
    const _Float16* const gAl2 = gA + (size_t)M_TOT * K_TOT;   // Al plane
    const _Float16* const gBl2 = gB + (size_t)N_TOT * K_TOT;   // Bl plane
    const int t8 = t * 8;

    int aof[4][2], bof[2][2];
    #pragma unroll
    for (int mi = 0; mi < 4; ++mi) {
        int rr = wm + mi * 32 + m32;
        int x = (rr >> 1) & 3;
        #pragma unroll
        for (int kc = 0; kc < 2; ++kc)
            aof[mi][kc] = rr * 32 + (((kc * 2 + kql0) ^ x) * 8);
    }
    #pragma unroll
    for (int ni = 0; ni < 2; ++ni) {
        int rr = wn + ni * 32 + m32;
        int x = (rr >> 1) & 3;
        #pragma unroll
        for (int kc = 0; kc < 2; ++kc)
            bof[ni][kc] = rr * 32 + (((kc * 2 + kql0) ^ x) * 8);
    }

    f32x16 acc[4][2] = {};

    // ---- prologue: stage tile 0, issue order Ah, Bl, Bh, Al ----
    {
        _Float16* L0 = lds + t8;
        ld_lds16(gA,            L0);
        ld_lds16(gA  + 65536,   L0 + 4096);
        ld_lds16(gBl2,          L0 + 3 * 8192);
        ld_lds16(gBl2 + 65536,  L0 + 3 * 8192 + 4096);
        ld_lds16(gB,            L0 + 2 * 8192);
        ld_lds16(gB  + 65536,   L0 + 2 * 8192 + 4096);
        ld_lds16(gAl2,          L0 + 1 * 8192);
        ld_lds16(gAl2 + 65536,  L0 + 1 * 8192 + 4096);
        VMC(4);          // Ah(0), Bl(0) landed; Bh(0), Al(0) in flight
        BAR();
    }

    #pragma unroll 1
    for (int tt = 0; tt < 16; ++tt) {
        const int cb = (tt & 1) << 15;
        const _Float16* Lc = lds + cb;
        _Float16* Ln = lds + (cb ^ 32768) + t8;
        const int kk = tt * 32 + 32;
        const bool st = (tt < 15);

        f16x8 faH[4][2], faL[4][2], fbH[2][2], fbL[2][2];

        // ==== PH1: read Ah(Q0), Bl; MFMA hl-Q0 ====
        #pragma unroll
        for (int mi = 0; mi < 2; ++mi)
            #pragma unroll
            for (int kc = 0; kc < 2; ++kc)
                faH[mi][kc] = *(const f16x8*)(Lc + aof[mi][kc]);
        #pragma unroll
        for (int ni = 0; ni < 2; ++ni)
            #pragma unroll
            for (int kc = 0; kc < 2; ++kc)
                fbL[ni][kc] = *(const f16x8*)(Lc + 3 * 8192 + bof[ni][kc]);
        if (st) {
            ld_lds16(gA + kk,         Ln);
            ld_lds16(gA + kk + 65536, Ln + 4096);
        }
        BAR();
        __builtin_amdgcn_s_setprio(1);
        #pragma unroll
        for (int mi = 0; mi < 2; ++mi)
            #pragma unroll
            for (int ni = 0; ni < 2; ++ni)
                #pragma unroll
                for (int kc = 0; kc < 2; ++kc)
                    acc[mi][ni] = __builtin_amdgcn_mfma_f32_32x32x16_f16(
                        faH[mi][kc], fbL[ni][kc], acc[mi][ni], 0, 0, 0);
        __builtin_amdgcn_s_setprio(0);
        if (st) VMC(4); else VMC(2);    // Bh(t) landed
        BAR();

        // ==== PH2: read Ah(Q1), Bh; MFMA hl-Q1 + hh-Q0 ====
        #pragma unroll
        for (int mi = 2; mi < 4; ++mi)
            #pragma unroll
            for (int kc = 0; kc < 2; ++kc)
                faH[mi][kc] = *(const f16x8*)(Lc + aof[mi][kc]);
        #pragma unroll
        for (int ni = 0; ni < 2; ++ni)
            #pragma unroll
            for (int kc = 0; kc < 2; ++kc)
                fbH[ni][kc] = *(const f16x8*)(Lc + 2 * 8192 + bof[ni][kc]);
        if (st) {
            ld_lds16(gBl2 + kk,         Ln + 3 * 8192);
            ld_lds16(gBl2 + kk + 65536, Ln + 3 * 8192 + 4096);
        }
        BAR();
        __builtin_amdgcn_s_setprio(1);
        #pragma unroll
        for (int mi = 2; mi < 4; ++mi)
            #pragma unroll
            for (int ni = 0; ni < 2; ++ni)
                #pragma unroll
                for (int kc = 0; kc < 2; ++kc)
                    acc[mi][ni] = __builtin_amdgcn_mfma_f32_32x32x16_f16(
                        faH[mi][kc], fbL[ni][kc], acc[mi][ni], 0, 0, 0);
        #pragma unroll
        for (int mi = 0; mi < 2; ++mi)
            #pragma unroll
            for (int ni = 0; ni < 2; ++ni)
                #pragma unroll
                for (int kc = 0; kc < 2; ++kc)
                    acc[mi][ni] = __builtin_amdgcn_mfma_f32_32x32x16_f16(
                        faH[mi][kc], fbH[ni][kc], acc[mi][ni], 0, 0, 0);
        __builtin_amdgcn_s_setprio(0);
        if (st) VMC(4); else VMC(0);    // Al(t) landed
        BAR();

        // ==== PH3: read Al; MFMA hh-Q1 + lh-all ====
        #pragma unroll
        for (int mi = 0; mi < 4; ++mi)
            #pragma unroll
            for (int kc = 0; kc < 2; ++kc)
                faL[mi][kc] = *(const f16x8*)(Lc + 1 * 8192 + aof[mi][kc]);
        if (st) {
            ld_lds16(gB   + kk,         Ln + 2 * 8192);
            ld_lds16(gB   + kk + 65536, Ln + 2 * 8192 + 4096);
            ld_lds16(gAl2 + kk,         Ln + 1 * 8192);
            ld_lds16(gAl2 + kk + 65536, Ln + 1 * 8192 + 4096);
        }
        BAR();
        __builtin_amdgcn_s_setprio(1);
        #pragma unroll
        for (int mi = 2; mi < 4; ++mi)
            #pragma unroll
            for (int ni = 0; ni < 2; ++ni)
                #pragma unroll
                for (int kc = 0; kc < 2; ++kc)
                    acc[mi][ni] = __builtin_amdgcn_mfma_f32_32x32x16_f16(
                        faH[mi][kc], fbH[ni][kc], acc[mi][ni], 0, 0, 0);
        #pragma unroll
        for (int mi = 0; mi < 4; ++mi)
            #pragma unroll
            for (int ni = 0; ni < 2; ++ni)
                #pragma unroll
                for (int kc = 0; kc < 2; ++kc)
                    acc[mi][ni] = __builtin_amdgcn_mfma_f32_32x32x16_f16(
                        faL[mi][kc], fbH[ni][kc], acc[mi][ni], 0, 0, 0);
        __builtin_amdgcn_s_setprio(0);
        if (st) VMC(4);                 // Ah(t+1), Bl(t+1) landed
        BAR();
    }

    // ---- epilogue: norm-correct + store ----
    const int rq = 4 * kql0;
    #pragma unroll
    for (int ni = 0; ni < 2; ++ni) {
        const int gc = gn0 + wn + ni * 32 + m32;
        const int nn = gc >> 7;
        const int col = gc & 127;
        const bool cn = (col < 16);
        const float nf = cn ? normf[gc] : 1.f;
        #pragma unroll
        for (int mi = 0; mi < 4; ++mi) {
            #pragma unroll
            for (int reg = 0; reg < 16; ++reg) {
                const int gm = gm0 + wm + mi * 32 + (reg & 3) + 8 * (reg >> 2) + rq;
                const int mm = gm >> 4, ii = gm & 15;
                float v = acc[mi][ni][reg];
                if (cn && col <= ii) v /= nf;
                out[(((size_t)mm * 128 + nn) * 16 + ii) * 128 + col] = v;
            }
        }
    }
}

// ---------------- Kernel 3: wavefront DTW, single-wave blocks, depth-4 prefetch ----------------
// R7: every window load is issued >=64 DP-steps (~1200 cyc) before its WSTORE,
// covering the ~900-cyc HBM miss latency (R5's ring issued only 32 steps ahead
// -> ~300-cyc stall per staging point). 4-window register ring (16 float4);
// compiler derives the counted vmcnts from register deps. Values bit-identical.
#define WQS 304        // per-problem stride (floats): 16*18 + 16 (==16 mod 32)
#define WBUF 1216      // per-buffer stride: 4*WQS

__device__ __forceinline__ float dpp_shr1_f32(float x) {
    union { float f; int i; } u, v;
    u.f = x;
    v.i = __builtin_amdgcn_update_dpp(u.i, u.i, 0x111, 0xF, 0xF, false);
    return v.f;
}

__global__ __launch_bounds__(64) void dtw_kernel(float* __restrict__ buf)
{
    __shared__ float swin[2 * WBUF];
    __shared__ uint32_t mvw[4][132];
    __shared__ int bounds[4][16];

    const int lane = threadIdx.x & 63;
    const int q = lane >> 4, r = lane & 15;
    const int pbase = (4095 - (int)blockIdx.x) * 4;
    const float4* gbase = (const float4*)(buf + (size_t)pbase * 2048);
    float* sw = swin;
    uint32_t* mvq = &mvw[q][0];

    int gidx[4], lidx[4];
    #pragma unroll
    for (int i = 0; i < 4; ++i) {
        gidx[i] = i * 512 + ((lane >> 2) & 15) * 32 + (lane & 3);
        lidx[i] = i * WQS + ((lane >> 2) & 15) * 18 + (lane & 3) * 4;
    }

#define WSTORE(regs, boff)                                                      \
    {                                                                           \
        _Pragma("unroll")                                                       \
        for (int i = 0; i < 4; ++i) {                                           \
            *(float2*)(sw + (boff) + lidx[i])     = make_float2(regs[i].x, regs[i].y); \
            *(float2*)(sw + (boff) + lidx[i] + 2) = make_float2(regs[i].z, regs[i].w); \
        }                                                                       \
    }
#define WLOAD(regs, win)                                                        \
    {                                                                           \
        _Pragma("unroll")                                                       \
        for (int i = 0; i < 4; ++i) regs[i] = gbase[gidx[i] + (win) * 4];       \
    }

    float4 W0[4], W1[4], W2[4], W3[4];
    WLOAD(W0, 0) WLOAD(W1, 1) WLOAD(W2, 2) WLOAD(W3, 3)
    WSTORE(W0, 0)                     // win0 -> buf0
    WSTORE(W1, WBUF)                  // win1 -> buf1
    WLOAD(W0, 4) WLOAD(W1, 5)         // refill ring: win4, win5 in flight

    const float NEG = -1e30f;
    float Dp = NEG, rawprev = NEG;
    uint32_t mvbuf = 0;
    int j = -r;
    const int sb = q * WQS + r * 18;

#define DTW_STEP(BOUNDARY)                                                      \
    {                                                                           \
        float upr = dpp_shr1_f32(Dp);                                           \
        float dg = rawprev;                                                     \
        rawprev = upr;                                                          \
        float up = (r == 0) ? NEG : upr;                                        \
        float lf = Dp;                                                          \
        if (BOUNDARY) {                                                         \
            if (j == 0) { lf = NEG; dg = (r == 0) ? 0.0f : NEG; }               \
            else if (r == 0) dg = NEG;                                          \
        } else {                                                                \
            if (r == 0) dg = NEG;                                               \
        }                                                                       \
        float sv = sw[(((j >> 4) & 1) ? WBUF : 0) + sb + (j & 15)];             \
        int m = (up >= lf && up >= dg) ? 0 : ((lf >= dg) ? 1 : 2);              \
        float Dc = fmaxf(up, fmaxf(lf, dg)) + sv;                               \
        if ((unsigned)j < 128u) {                                               \
            mvbuf |= (uint32_t)m << (2 * (j & 15));                             \
            if ((j & 15) == 15) { mvq[r * 8 + (j >> 4)] = mvbuf; mvbuf = 0; }   \
        }                                                                       \
        Dp = Dc;                                                                \
        ++j;                                                                    \
    }

    for (int tt = 0; tt < 16; ++tt) DTW_STEP(true)
    for (int tt = 16; tt < 32; ++tt) DTW_STEP(false)
    WSTORE(W2, 0)      /* win2 -> buf0 */  WLOAD(W2, 6)
    for (int tt = 32; tt < 48; ++tt) DTW_STEP(false)
    WSTORE(W3, WBUF)   /* win3 -> buf1 */  WLOAD(W3, 7)
    for (int tt = 48; tt < 64; ++tt) DTW_STEP(false)
    WSTORE(W0, 0)      /* win4 -> buf0 */
    for (int tt = 64; tt < 80; ++tt) DTW_STEP(false)
    WSTORE(W1, WBUF)   /* win5 -> buf1 */
    for (int tt = 80; tt < 96; ++tt) DTW_STEP(false)
    WSTORE(W2, 0)      /* win6 -> buf0 */
    for (int tt = 96; tt < 112; ++tt) DTW_STEP(false)
    WSTORE(W3, WBUF)   /* win7 -> buf1 */
    for (int tt = 112; tt < 143; ++tt) DTW_STEP(false)
#undef DTW_STEP
#undef WSTORE
#undef WLOAD

    __syncthreads();

    if (r == 0) {
        int i = 16, jj = 128, hic = 127;
        int cidx = -1;
        uint32_t word = 0;
        for (int it = 0; it < 160; ++it) {
            if (i <= 0) break;
            int idx = (i - 1) * 8 + ((jj - 1) >> 4);
            if (idx != cidx) { word = mvq[idx]; cidx = idx; }
            int m = (int)((word >> (2 * ((jj - 1) & 15))) & 3u);
            if (m == 1) { --jj; continue; }
            bounds[q][i - 1] = (jj - 1) | (hic << 8);
            if (m == 2) --jj;
            --i;
            hic = jj - 1;
        }
    }
    __syncthreads();

    #pragma unroll 4
    for (int it = 0; it < 32; ++it) {
        int flat = it * 64 + lane;
        int q2 = flat >> 9;
        int rem = flat & 511;
        int ii = rem >> 5;
        int c4 = rem & 31;
        int b = bounds[q2][ii];
        int lo = b & 0xff, hi = (b >> 8) & 0xff;
        int j0 = c4 * 4;
        float4 v;
        v.x = (j0 + 0 >= lo && j0 + 0 <= hi) ? 1.f : 0.f;
        v.y = (j0 + 1 >= lo && j0 + 1 <= hi) ? 1.f : 0.f;
        v.z = (j0 + 2 >= lo && j0 + 2 <= hi) ? 1.f : 0.f;
        v.w = (j0 + 3 >= lo && j0 + 3 <= hi) ? 1.f : 0.f;
        float* tb = buf + (size_t)(pbase + q2) * 2048;
        *(float4*)(tb + ii * 128 + j0) = v;
    }
}

extern "C" void kernel_launch(void* const* d_in, const int* in_sizes, int n_in,
                              void* d_out, int out_size, void* d_ws, size_t ws_size,
                              hipStream_t stream)
{
    const float* c_feats = (const float*)d_in[0];
    const float* f_feats = (const float*)d_in[1];
    float* out = (float*)d_out;

    _Float16* Ah = (_Float16*)d_ws;
    _Float16* Al = Ah + (size_t)M_TOT * K_TOT;
    _Float16* Bh = Al + (size_t)M_TOT * K_TOT;
    _Float16* Bl = Bh + (size_t)N_TOT * K_TOT;
    float* normf = (float*)(Bl + (size_t)N_TOT * K_TOT);

    norm_split_kernel<<<4608, 256, 0, stream>>>(c_feats, f_feats, Ah, Al, Bh, Bl, normf);
    dim3 g(N_TOT / 256, M_TOT / 256);
    mfma_gemm_kernel<<<g, 512, 0, stream>>>(Ah, Al, Bh, Bl, normf, out);
    dtw_kernel<<<4096, 64, 0, stream>>>(out);
}